// Round 10
// baseline (871.843 us; speedup 1.0000x reference)
//
#include <hip/hip_runtime.h>

#define DD 256
#define KK 8192
#define HW 1024
#define NROWS 16384
#define NELEM 4194304
#define MT 32
#define MARGIN 6e-4f
#define WCAP 512

typedef __attribute__((ext_vector_type(8))) short short8;
typedef __attribute__((ext_vector_type(4))) float f32x4;
typedef unsigned short ushort;
typedef unsigned int uint;
typedef unsigned long long u64;

// ---- exact replication of numpy pairwise_sum (n=256) over squares ----
__device__ __forceinline__ float np_pw128_sq(const float* p) {
  float r[8];
#pragma unroll
  for (int j = 0; j < 8; ++j) r[j] = __fmul_rn(p[j], p[j]);
  for (int i = 8; i < 128; i += 8) {
#pragma unroll
    for (int j = 0; j < 8; ++j)
      r[j] = __fadd_rn(r[j], __fmul_rn(p[i + j], p[i + j]));
  }
  return __fadd_rn(__fadd_rn(__fadd_rn(r[0], r[1]), __fadd_rn(r[2], r[3])),
                   __fadd_rn(__fadd_rn(r[4], r[5]), __fadd_rn(r[6], r[7])));
}

__device__ __forceinline__ ushort f2bf(float x) {   // RNE float->bf16 bits
  uint u = __float_as_uint(x);
  u += 0x7FFF + ((u >> 16) & 1);
  return (ushort)(u >> 16);
}

// order-preserving float<->uint for LDS atomicMin
__device__ __forceinline__ uint encf(float f) {
  uint u = __float_as_uint(f);
  return (u & 0x80000000u) ? ~u : (u | 0x80000000u);
}
__device__ __forceinline__ float decf(uint u) {
  return __uint_as_float((u & 0x80000000u) ? (u & 0x7FFFFFFFu) : ~u);
}

// ======== merged prep: transpose | norms | arow | cbB fragments ========
__global__ __launch_bounds__(256) void vq_prep(const float* __restrict__ z,
                                               const float* __restrict__ cb,
                                               float* __restrict__ cbT,
                                               float* __restrict__ Bk,
                                               float* __restrict__ Arow,
                                               ushort* __restrict__ cbB) {
  __shared__ float tile[64][65];
  const int b = blockIdx.x, t = threadIdx.x;
  if (b < 512) {               // cbT[d][k] = cb[k][d]
    int k0 = (b & 127) * 64, d0 = (b >> 7) * 64;
    for (int li = t; li < 64 * 64; li += 256) {
      int kk = li >> 6, dd = li & 63;
      tile[kk][dd] = cb[(size_t)(k0 + kk) * DD + d0 + dd];
    }
    __syncthreads();
    for (int li = t; li < 64 * 64; li += 256) {
      int dd = li >> 6, kk = li & 63;
      cbT[(size_t)(d0 + dd) * KK + k0 + kk] = tile[kk][dd];
    }
  } else if (b < 544) {        // ||e_k||^2, numpy-exact
    int k = (b - 512) * 256 + t;
    const float* p = cb + (size_t)k * DD;
    Bk[k] = __fadd_rn(np_pw128_sq(p), np_pw128_sq(p + 128));
  } else if (b < 608) {        // ||z_n||^2, numpy-exact (strided)
    int n = (b - 544) * 256 + t;
    int bimg = n >> 10, hw = n & 1023;
    const float* zp = z + (size_t)bimg * DD * HW + hw;
    float h[2];
#pragma unroll
    for (int half = 0; half < 2; ++half) {
      float r[8];
#pragma unroll
      for (int j = 0; j < 8; ++j) {
        float v = zp[(size_t)(half * 128 + j) * HW];
        r[j] = __fmul_rn(v, v);
      }
      for (int i = 8; i < 128; i += 8) {
#pragma unroll
        for (int j = 0; j < 8; ++j) {
          float v = zp[(size_t)(half * 128 + i + j) * HW];
          r[j] = __fadd_rn(r[j], __fmul_rn(v, v));
        }
      }
      h[half] = __fadd_rn(__fadd_rn(__fadd_rn(r[0], r[1]), __fadd_rn(r[2], r[3])),
                          __fadd_rn(__fadd_rn(r[4], r[5]), __fadd_rn(r[6], r[7])));
    }
    Arow[n] = __fadd_rn(h[0], h[1]);
  } else {                     // cbB fragments (layout verified r7/r8/r9)
    int tid = (b - 608) * 256 + t;
    int g = tid >> 9, s = (tid >> 6) & 7, lane = tid & 63;
    int code = g * 16 + (lane & 15);
    int dbase = s * 32 + (lane >> 4) * 8;
    const float* p = cb + (size_t)code * DD + dbase;
    ushort bb[8];
#pragma unroll
    for (int j = 0; j < 8; ++j) bb[j] = f2bf(p[j]);
    uint4 pk;
    pk.x = bb[0] | ((uint)bb[1] << 16);
    pk.y = bb[2] | ((uint)bb[3] << 16);
    pk.z = bb[4] | ((uint)bb[5] << 16);
    pk.w = bb[6] | ((uint)bb[7] << 16);
    *(uint4*)(cbB + (size_t)tid * 8) = pk;
  }
}

// ======== fused: LDS-staged MFMA screen + exact re-rank + epilogue ========
// Plain launch_bounds (r4/r5 lesson: min-waves arg caps VGPRs -> spill).
__global__ __launch_bounds__(256) void vq_fused(
    const float* __restrict__ z, const float* __restrict__ cbT,
    const float* __restrict__ cb, const ushort* __restrict__ cbB,
    const float* __restrict__ Bk, const float* __restrict__ Arow,
    float* __restrict__ out, int* __restrict__ hist,
    float* __restrict__ loss_acc, u64* __restrict__ rowBest) {
  __shared__ uint gmin_u[MT][128];     // 16 KB  (order-preserving uint mins)
  __shared__ ushort stage[16448];      // 32.9 KB union: code tiles / zt
  __shared__ float thr[MT];
  __shared__ float ArS[MT];
  __shared__ int wl[WCAP];
  __shared__ int wcnt;
  __shared__ int kwin[MT];
  __shared__ float lred[4];
  float (*zt)[DD + 1] = (float(*)[DD + 1])stage;

  const int t = threadIdx.x;
  const int n0 = blockIdx.x * MT;
  const int bimg = n0 >> 10, hw0 = n0 & 1023;
  const float* zb = z + (size_t)bimg * DD * HW + hw0;

  for (int i = t; i < MT * 128; i += 256) ((uint*)gmin_u)[i] = 0xFFFFFFFFu;
  if (t == 0) wcnt = 0;
  if (t < MT) ArS[t] = Arow[n0 + t];
  for (int li = t; li < MT * DD; li += 256) {
    int d = li >> 5, r = li & 31;
    zt[r][d] = zb[d * HW + r];
  }
  __syncthreads();

  const int w = t >> 6, lane = t & 63;
  const int cs = w;               // wave owns 16 codes of each 64-code tile
  const int quad = lane >> 4, n16 = lane & 15;

  // A-fragments for BOTH 16-row groups (m89-verified layout), in registers
  short8 aF[2][8];
#pragma unroll
  for (int rg = 0; rg < 2; ++rg)
#pragma unroll
    for (int s = 0; s < 8; ++s) {
      const float* zp = &zt[rg * 16 + n16][s * 32 + quad * 8];
      short8 v;
#pragma unroll
      for (int j = 0; j < 8; ++j) v[j] = (short)f2bf(zp[j]);
      aF[rg][s] = v;
    }

  // prologue: prefetch tile 0 (contiguous 32 KB chunk of cbB) into regs
  uint4 pre[8];
  {
    const uint4* src = (const uint4*)cbB;
#pragma unroll
    for (int i = 0; i < 8; ++i) pre[i] = src[i * 256 + t];
  }

  // ---- screen: 128 tiles x 64 codes; cbB read once/block via LDS ----
  for (int tile = 0; tile < 128; ++tile) {
    __syncthreads();   // prior tile's ds_reads done (also protects zt reads)
#pragma unroll
    for (int i = 0; i < 8; ++i) ((uint4*)stage)[i * 256 + t] = pre[i];
    __syncthreads();   // staged tile visible
    if (tile < 127) {  // prefetch next tile during this tile's compute
      const uint4* src = (const uint4*)(cbB + (size_t)(tile + 1) * 16384);
#pragma unroll
      for (int i = 0; i < 8; ++i) pre[i] = src[i * 256 + t];
    }
    f32x4 acc0 = {0.f, 0.f, 0.f, 0.f}, acc1 = {0.f, 0.f, 0.f, 0.f};
#pragma unroll
    for (int s = 0; s < 8; ++s) {
      short8 bF = *(const short8*)(stage + ((size_t)((cs * 8 + s) * 64 + lane) * 8));
      acc0 = __builtin_amdgcn_mfma_f32_16x16x32_bf16(aF[0][s], bF, acc0, 0, 0, 0);
      acc1 = __builtin_amdgcn_mfma_f32_16x16x32_bf16(aF[1][s], bF, acc1, 0, 0, 0);
    }
    const float Bs = Bk[(tile << 6) + (cs << 4) + n16];
    float sv0[4], sv1[4];
#pragma unroll
    for (int reg = 0; reg < 4; ++reg) {
      sv0[reg] = fmaf(-2.f, acc0[reg], Bs);
      sv1[reg] = fmaf(-2.f, acc1[reg], Bs);
    }
#pragma unroll
    for (int off = 1; off < 16; off <<= 1)
#pragma unroll
      for (int reg = 0; reg < 4; ++reg) {
        sv0[reg] = fminf(sv0[reg], __shfl_xor(sv0[reg], off));
        sv1[reg] = fminf(sv1[reg], __shfl_xor(sv1[reg], off));
      }
    if (n16 == 0) {
#pragma unroll
      for (int reg = 0; reg < 4; ++reg) {
        atomicMin(&gmin_u[quad * 4 + reg][tile], encf(sv0[reg]));
        atomicMin(&gmin_u[16 + quad * 4 + reg][tile], encf(sv1[reg]));
      }
    }
  }
  __syncthreads();

  // restage zt (union area was overwritten by the screen)
  for (int li = t; li < MT * DD; li += 256) {
    int d = li >> 5, r = li & 31;
    zt[r][d] = zb[d * HW + r];
  }
  if (t < MT) {
    uint mu = 0xFFFFFFFFu;
    for (int c = 0; c < 128; ++c) mu = min(mu, gmin_u[t][c]);
    thr[t] = decf(mu) + MARGIN;
  }
  __syncthreads();

  // ---- worklist build ----
  for (int idx = t; idx < MT * 128; idx += 256) {
    int r = idx >> 7, g = idx & 127;
    if (decf(gmin_u[r][g]) <= thr[r]) {
      int pos = atomicAdd(&wcnt, 1);
      if (pos < WCAP) {
        wl[pos] = (r << 16) | g;
      } else {   // overflow fallback (never in practice): scalar exact scan
        float bd = 3.4e38f;
        int bi = 0;
        for (int c = 0; c < 64; ++c) {
          int code = g * 64 + c;
          const float* ep = cb + (size_t)code * DD;
          float dot = 0.f;
          for (int d = 0; d < DD; ++d) dot = fmaf(zt[r][d], ep[d], dot);
          float dist = __fsub_rn(__fadd_rn(ArS[r], Bk[code]),
                                 __fmul_rn(2.f, dot));
          if (dist < bd) { bd = dist; bi = code; }
        }
        atomicMin(&rowBest[n0 + r],
                  ((u64)__float_as_uint(bd) << 32) | (unsigned)bi);
      }
    }
  }
  __syncthreads();

  // ---- exact re-rank: one wave per flagged (row, 64-code group) ----
  // batched strided loads (r9) + ascending-d fmaf chain (numpy-exact order)
  const int cnt = min(wcnt, WCAP);
  for (int e = w; e < cnt; e += 4) {
    const int ent = wl[e];
    const int r = ent >> 16, g = ent & 0xFFFF;
    const int code = g * 64 + lane;
    const float* cp = cbT + code;
    float dot = 0.f;
#pragma unroll
    for (int d0 = 0; d0 < DD; d0 += 64) {
      float v[64];
#pragma unroll
      for (int j = 0; j < 64; ++j) v[j] = cp[(size_t)(d0 + j) * KK];
#pragma unroll
      for (int j = 0; j < 64; ++j) dot = fmaf(zt[r][d0 + j], v[j], dot);
    }
    float bd = __fsub_rn(__fadd_rn(ArS[r], Bk[code]), __fmul_rn(2.f, dot));
    int bi = code;
#pragma unroll
    for (int off = 1; off < 64; off <<= 1) {   // lex (dist, idx) min
      float pd = __shfl_xor(bd, off);
      int pi = __shfl_xor(bi, off);
      if (pd < bd || (pd == bd && pi < bi)) { bd = pd; bi = pi; }
    }
    if (lane == 0)
      atomicMin(&rowBest[n0 + r],
                ((u64)__float_as_uint(bd) << 32) | (unsigned)bi);
  }
  __syncthreads();

  // ---- epilogue: indices + hist + z_q_st + loss (zt resident) ----
  if (t < MT) {
    u64 key = atomicMin(&rowBest[n0 + t], 0xFFFFFFFFFFFFFFFFull);  // read
    int bi = (int)(key & 0xFFFFFFFFull);
    kwin[t] = bi;
    atomicAdd(&hist[bi], 1);
    out[(size_t)NELEM + 1 + n0 + t] = (float)bi;
  }
  __syncthreads();

  float lsum = 0.f;
  for (int it = 0; it < MT * DD / 256; ++it) {
    int li = it * 256 + t;
    int d = li >> 5, r = li & 31;
    float ze = zt[r][d];
    float zq = cb[(size_t)kwin[r] * DD + d];
    float diff = __fsub_rn(zq, ze);
    float st = __fadd_rn(ze, diff);        // z_e + (z_q - z_e)
    out[(size_t)(bimg * DD + d) * HW + hw0 + r] = st;
    lsum = fmaf(diff, diff, lsum);
  }
#pragma unroll
  for (int off = 32; off > 0; off >>= 1) lsum += __shfl_down(lsum, off);
  if (lane == 0) lred[w] = lsum;
  __syncthreads();
  if (t == 0)
    atomicAdd(loss_acc, ((lred[0] + lred[1]) + (lred[2] + lred[3])));
}

// ---------------- finalize: vq_loss + perplexity ----------------
__global__ __launch_bounds__(256) void vq_final(const int* __restrict__ hist,
                                                const float* __restrict__ loss,
                                                float* __restrict__ out) {
  __shared__ float sred[256];
  int t = threadIdx.x;
  float s = 0.f;
  for (int k = t; k < KK; k += 256) {
    float p = (float)hist[k] * (1.f / 16384.f);
    s += p * logf(p + 1e-10f);
  }
  sred[t] = s;
  __syncthreads();
  for (int off = 128; off > 0; off >>= 1) {
    if (t < off) sred[t] += sred[t + off];
    __syncthreads();
  }
  if (t == 0) {
    float L = loss[0] / (float)NELEM;
    out[NELEM] = 1.25f * L;
    out[(size_t)NELEM + 1 + NROWS] = expf(-sred[0]);
  }
}

extern "C" void kernel_launch(void* const* d_in, const int* in_sizes, int n_in,
                              void* d_out, int out_size, void* d_ws, size_t ws_size,
                              hipStream_t stream) {
  const float* z = (const float*)d_in[0];   // (16,256,32,32) fp32
  const float* cb = (const float*)d_in[1];  // (8192,256) fp32
  float* out = (float*)d_out;               // fp32: [z_q_st | loss | idx | perp]

  float* wsf = (float*)d_ws;
  int* hist = (int*)d_ws;                          // 8192 ints
  float* loss = wsf + 8192;                        // 1 (+pad)
  float* Bk = wsf + 8448;                          // 8192
  float* Arow = wsf + 16640;                       // 16384
  u64* rowBest = (u64*)(wsf + 33024);              // 16384 u64 (128 KB)
  ushort* cbB = (ushort*)(wsf + 65792);            // 2.10M ushorts (4.2 MB)
  float* cbT = wsf + 65792 + 1048576;              // 2M floats (8 MB)

  hipMemsetAsync(d_ws, 0, 8448 * sizeof(float), stream);
  hipMemsetAsync(rowBest, 0xFF, NROWS * sizeof(u64), stream);
  vq_prep<<<1632, 256, 0, stream>>>(z, cb, cbT, Bk, Arow, cbB);
  vq_fused<<<NROWS / MT, 256, 0, stream>>>(z, cbT, cb, cbB, Bk, Arow, out,
                                           hist, loss, rowBest);
  vq_final<<<1, 256, 0, stream>>>(hist, loss, out);
}

// Round 11
// 419.085 us; speedup vs baseline: 2.0803x; 2.0803x over previous
//
#include <hip/hip_runtime.h>

#define DD 256
#define KK 8192
#define HW 1024
#define NROWS 16384
#define NELEM 4194304
#define MT 32
#define MARGIN 6e-4f
#define WCAP 512

typedef __attribute__((ext_vector_type(8))) short short8;
typedef __attribute__((ext_vector_type(4))) float f32x4;
typedef unsigned short ushort;
typedef unsigned int uint;
typedef unsigned long long u64;

// ---- exact replication of numpy pairwise_sum (n=256) over squares ----
__device__ __forceinline__ float np_pw128_sq(const float* p) {
  float r[8];
#pragma unroll
  for (int j = 0; j < 8; ++j) r[j] = __fmul_rn(p[j], p[j]);
  for (int i = 8; i < 128; i += 8) {
#pragma unroll
    for (int j = 0; j < 8; ++j)
      r[j] = __fadd_rn(r[j], __fmul_rn(p[i + j], p[i + j]));
  }
  return __fadd_rn(__fadd_rn(__fadd_rn(r[0], r[1]), __fadd_rn(r[2], r[3])),
                   __fadd_rn(__fadd_rn(r[4], r[5]), __fadd_rn(r[6], r[7])));
}

__device__ __forceinline__ ushort f2bf(float x) {   // RNE float->bf16 bits
  uint u = __float_as_uint(x);
  u += 0x7FFF + ((u >> 16) & 1);
  return (ushort)(u >> 16);
}

// ======== merged prep: transpose | norms | arow | cbB fragments ========
__global__ __launch_bounds__(256) void vq_prep(const float* __restrict__ z,
                                               const float* __restrict__ cb,
                                               float* __restrict__ cbT,
                                               float* __restrict__ Bk,
                                               float* __restrict__ Arow,
                                               ushort* __restrict__ cbB) {
  __shared__ float tile[64][65];
  const int b = blockIdx.x, t = threadIdx.x;
  if (b < 512) {               // cbT[d][k] = cb[k][d]
    int k0 = (b & 127) * 64, d0 = (b >> 7) * 64;
    for (int li = t; li < 64 * 64; li += 256) {
      int kk = li >> 6, dd = li & 63;
      tile[kk][dd] = cb[(size_t)(k0 + kk) * DD + d0 + dd];
    }
    __syncthreads();
    for (int li = t; li < 64 * 64; li += 256) {
      int dd = li >> 6, kk = li & 63;
      cbT[(size_t)(d0 + dd) * KK + k0 + kk] = tile[kk][dd];
    }
  } else if (b < 544) {        // ||e_k||^2, numpy-exact
    int k = (b - 512) * 256 + t;
    const float* p = cb + (size_t)k * DD;
    Bk[k] = __fadd_rn(np_pw128_sq(p), np_pw128_sq(p + 128));
  } else if (b < 608) {        // ||z_n||^2, numpy-exact (strided)
    int n = (b - 544) * 256 + t;
    int bimg = n >> 10, hw = n & 1023;
    const float* zp = z + (size_t)bimg * DD * HW + hw;
    float h[2];
#pragma unroll
    for (int half = 0; half < 2; ++half) {
      float r[8];
#pragma unroll
      for (int j = 0; j < 8; ++j) {
        float v = zp[(size_t)(half * 128 + j) * HW];
        r[j] = __fmul_rn(v, v);
      }
      for (int i = 8; i < 128; i += 8) {
#pragma unroll
        for (int j = 0; j < 8; ++j) {
          float v = zp[(size_t)(half * 128 + i + j) * HW];
          r[j] = __fadd_rn(r[j], __fmul_rn(v, v));
        }
      }
      h[half] = __fadd_rn(__fadd_rn(__fadd_rn(r[0], r[1]), __fadd_rn(r[2], r[3])),
                          __fadd_rn(__fadd_rn(r[4], r[5]), __fadd_rn(r[6], r[7])));
    }
    Arow[n] = __fadd_rn(h[0], h[1]);
  } else {                     // cbB fragments (layout verified r7/r8/r9)
    int tid = (b - 608) * 256 + t;
    int g = tid >> 9, s = (tid >> 6) & 7, lane = tid & 63;
    int code = g * 16 + (lane & 15);
    int dbase = s * 32 + (lane >> 4) * 8;
    const float* p = cb + (size_t)code * DD + dbase;
    ushort bb[8];
#pragma unroll
    for (int j = 0; j < 8; ++j) bb[j] = f2bf(p[j]);
    uint4 pk;
    pk.x = bb[0] | ((uint)bb[1] << 16);
    pk.y = bb[2] | ((uint)bb[3] << 16);
    pk.z = bb[4] | ((uint)bb[5] << 16);
    pk.w = bb[6] | ((uint)bb[7] << 16);
    *(uint4*)(cbB + (size_t)tid * 8) = pk;
  }
}

// ======== fused: barrier-free pipelined MFMA screen + exact + epilogue ======
// Plain launch_bounds (r4/r5 lesson: min-waves arg caps VGPRs -> spill).
__global__ __launch_bounds__(256) void vq_fused(
    const float* __restrict__ z, const float* __restrict__ cbT,
    const float* __restrict__ cb, const ushort* __restrict__ cbB,
    const float* __restrict__ Bk, const float* __restrict__ Arow,
    float* __restrict__ out, int* __restrict__ hist,
    float* __restrict__ loss_acc, u64* __restrict__ rowBest) {
  __shared__ float zt[MT][DD + 1];    // 32.9 KB, staged once, lives to the end
  __shared__ float gmin[MT][129];     // 16.5 KB (pad: kills 32-way col scan)
  __shared__ float thr[MT];
  __shared__ float ArS[MT];
  __shared__ int wl[WCAP];
  __shared__ int wcnt;
  __shared__ int kwin[MT];
  __shared__ float lred[4];

  const int t = threadIdx.x;
  const int n0 = blockIdx.x * MT;
  const int bimg = n0 >> 10, hw0 = n0 & 1023;
  const float* zb = z + (size_t)bimg * DD * HW + hw0;

  if (t == 0) wcnt = 0;
  if (t < MT) ArS[t] = Arow[n0 + t];
  for (int li = t; li < MT * DD; li += 256) {
    int d = li >> 5, r = li & 31;
    zt[r][d] = zb[d * HW + r];
  }
  __syncthreads();

  const int w = t >> 6, lane = t & 63;
  const int quad = lane >> 4, n16 = lane & 15;

  // A-fragments for BOTH 16-row groups (m89-verified layout), in registers.
  // Each bF load then feeds TWO independent MFMA chains (2x work/load), and
  // cbB is read once per block (halves L2-miss traffic vs r9).
  short8 aF[2][8];
#pragma unroll
  for (int rg = 0; rg < 2; ++rg)
#pragma unroll
    for (int s = 0; s < 8; ++s) {
      const float* zp = &zt[rg * 16 + n16][s * 32 + quad * 8];
      short8 v;
#pragma unroll
      for (int j = 0; j < 8; ++j) v[j] = (short)f2bf(zp[j]);
      aF[rg][s] = v;
    }

  // ---- screen: wave owns 2048 codes = 128 groups of 16; no barriers ----
  const int g0 = w * 128;     // my first 16-code group (of 512 global)
  float m40[4] = {3.4e38f, 3.4e38f, 3.4e38f, 3.4e38f};
  float m41[4] = {3.4e38f, 3.4e38f, 3.4e38f, 3.4e38f};

  short8 b0[8], b1[8];
  {
    const ushort* bp = cbB + (size_t)g0 * 4096 + lane * 8;
#pragma unroll
    for (int s = 0; s < 8; ++s) b0[s] = *(const short8*)(bp + s * 512);
  }

  for (int gp = 0; gp < 64; ++gp) {     // hand-pipelined pairs: b0/b1 ping-pong
    const int gg = g0 + gp * 2;
    {   // prefetch odd group while even computes
      const ushort* bp = cbB + (size_t)(gg + 1) * 4096 + lane * 8;
#pragma unroll
      for (int s = 0; s < 8; ++s) b1[s] = *(const short8*)(bp + s * 512);
    }
    {   // even group
      f32x4 a0 = {0.f, 0.f, 0.f, 0.f}, a1 = {0.f, 0.f, 0.f, 0.f};
#pragma unroll
      for (int s = 0; s < 8; ++s) {
        a0 = __builtin_amdgcn_mfma_f32_16x16x32_bf16(aF[0][s], b0[s], a0, 0, 0, 0);
        a1 = __builtin_amdgcn_mfma_f32_16x16x32_bf16(aF[1][s], b0[s], a1, 0, 0, 0);
      }
      const float Bs = Bk[gg * 16 + n16];
#pragma unroll
      for (int reg = 0; reg < 4; ++reg) {
        m40[reg] = fminf(m40[reg], fmaf(-2.f, a0[reg], Bs));
        m41[reg] = fminf(m41[reg], fmaf(-2.f, a1[reg], Bs));
      }
    }
    if (gp < 63) {   // prefetch next even group while odd computes
      const ushort* bp = cbB + (size_t)(gg + 2) * 4096 + lane * 8;
#pragma unroll
      for (int s = 0; s < 8; ++s) b0[s] = *(const short8*)(bp + s * 512);
    }
    {   // odd group
      f32x4 a0 = {0.f, 0.f, 0.f, 0.f}, a1 = {0.f, 0.f, 0.f, 0.f};
#pragma unroll
      for (int s = 0; s < 8; ++s) {
        a0 = __builtin_amdgcn_mfma_f32_16x16x32_bf16(aF[0][s], b1[s], a0, 0, 0, 0);
        a1 = __builtin_amdgcn_mfma_f32_16x16x32_bf16(aF[1][s], b1[s], a1, 0, 0, 0);
      }
      const float Bs = Bk[(gg + 1) * 16 + n16];
#pragma unroll
      for (int reg = 0; reg < 4; ++reg) {
        m40[reg] = fminf(m40[reg], fmaf(-2.f, a0[reg], Bs));
        m41[reg] = fminf(m41[reg], fmaf(-2.f, a1[reg], Bs));
      }
    }
    if (gp & 1) {    // 4 groups (64 codes) done: reduce over 16 code-lanes
#pragma unroll
      for (int off = 1; off < 16; off <<= 1)
#pragma unroll
        for (int reg = 0; reg < 4; ++reg) {
          m40[reg] = fminf(m40[reg], __shfl_xor(m40[reg], off));
          m41[reg] = fminf(m41[reg], __shfl_xor(m41[reg], off));
        }
      if (n16 == 0) {
        const int tile = (gg + 1) >> 2;   // wave-disjoint tiles: plain stores
#pragma unroll
        for (int reg = 0; reg < 4; ++reg) {
          gmin[quad * 4 + reg][tile] = m40[reg];
          gmin[16 + quad * 4 + reg][tile] = m41[reg];
        }
      }
#pragma unroll
      for (int reg = 0; reg < 4; ++reg) { m40[reg] = 3.4e38f; m41[reg] = 3.4e38f; }
    }
  }
  __syncthreads();

  // ---- per-row global threshold ----
  if (t < MT) {
    float mn = gmin[t][0];
    for (int c = 1; c < 128; ++c) mn = fminf(mn, gmin[t][c]);
    thr[t] = mn + MARGIN;
  }
  __syncthreads();

  // ---- worklist build ----
  for (int idx = t; idx < MT * 128; idx += 256) {
    int r = idx >> 7, g = idx & 127;
    if (gmin[r][g] <= thr[r]) {
      int pos = atomicAdd(&wcnt, 1);
      if (pos < WCAP) {
        wl[pos] = (r << 16) | g;
      } else {   // overflow fallback (never in practice): scalar exact scan
        float bd = 3.4e38f;
        int bi = 0;
        for (int c = 0; c < 64; ++c) {
          int code = g * 64 + c;
          const float* ep = cb + (size_t)code * DD;
          float dot = 0.f;
          for (int d = 0; d < DD; ++d) dot = fmaf(zt[r][d], ep[d], dot);
          float dist = __fsub_rn(__fadd_rn(ArS[r], Bk[code]),
                                 __fmul_rn(2.f, dot));
          if (dist < bd) { bd = dist; bi = code; }
        }
        atomicMin(&rowBest[n0 + r],
                  ((u64)__float_as_uint(bd) << 32) | (unsigned)bi);
      }
    }
  }
  __syncthreads();

  // ---- exact re-rank: one wave per flagged (row, 64-code group) ----
  // batched strided loads (r9) + ascending-d fmaf chain (numpy-exact order)
  const int cnt = min(wcnt, WCAP);
  for (int e = w; e < cnt; e += 4) {
    const int ent = wl[e];
    const int r = ent >> 16, g = ent & 0xFFFF;
    const int code = g * 64 + lane;
    const float* cp = cbT + code;
    float dot = 0.f;
#pragma unroll
    for (int d0 = 0; d0 < DD; d0 += 64) {
      float v[64];
#pragma unroll
      for (int j = 0; j < 64; ++j) v[j] = cp[(size_t)(d0 + j) * KK];
#pragma unroll
      for (int j = 0; j < 64; ++j) dot = fmaf(zt[r][d0 + j], v[j], dot);
    }
    float bd = __fsub_rn(__fadd_rn(ArS[r], Bk[code]), __fmul_rn(2.f, dot));
    int bi = code;
#pragma unroll
    for (int off = 1; off < 64; off <<= 1) {   // lex (dist, idx) min
      float pd = __shfl_xor(bd, off);
      int pi = __shfl_xor(bi, off);
      if (pd < bd || (pd == bd && pi < bi)) { bd = pd; bi = pi; }
    }
    if (lane == 0)
      atomicMin(&rowBest[n0 + r],
                ((u64)__float_as_uint(bd) << 32) | (unsigned)bi);
  }
  __syncthreads();

  // ---- epilogue: indices + hist + z_q_st + loss (zt resident) ----
  if (t < MT) {
    u64 key = atomicMin(&rowBest[n0 + t], 0xFFFFFFFFFFFFFFFFull);  // read
    int bi = (int)(key & 0xFFFFFFFFull);
    kwin[t] = bi;
    atomicAdd(&hist[bi], 1);
    out[(size_t)NELEM + 1 + n0 + t] = (float)bi;
  }
  __syncthreads();

  float lsum = 0.f;
  for (int it = 0; it < MT * DD / 256; ++it) {
    int li = it * 256 + t;
    int d = li >> 5, r = li & 31;
    float ze = zt[r][d];
    float zq = cb[(size_t)kwin[r] * DD + d];
    float diff = __fsub_rn(zq, ze);
    float st = __fadd_rn(ze, diff);        // z_e + (z_q - z_e)
    out[(size_t)(bimg * DD + d) * HW + hw0 + r] = st;
    lsum = fmaf(diff, diff, lsum);
  }
#pragma unroll
  for (int off = 32; off > 0; off >>= 1) lsum += __shfl_down(lsum, off);
  if (lane == 0) lred[w] = lsum;
  __syncthreads();
  if (t == 0)
    atomicAdd(loss_acc, ((lred[0] + lred[1]) + (lred[2] + lred[3])));
}

// ---------------- finalize: vq_loss + perplexity ----------------
__global__ __launch_bounds__(256) void vq_final(const int* __restrict__ hist,
                                                const float* __restrict__ loss,
                                                float* __restrict__ out) {
  __shared__ float sred[256];
  int t = threadIdx.x;
  float s = 0.f;
  for (int k = t; k < KK; k += 256) {
    float p = (float)hist[k] * (1.f / 16384.f);
    s += p * logf(p + 1e-10f);
  }
  sred[t] = s;
  __syncthreads();
  for (int off = 128; off > 0; off >>= 1) {
    if (t < off) sred[t] += sred[t + off];
    __syncthreads();
  }
  if (t == 0) {
    float L = loss[0] / (float)NELEM;
    out[NELEM] = 1.25f * L;
    out[(size_t)NELEM + 1 + NROWS] = expf(-sred[0]);
  }
}

extern "C" void kernel_launch(void* const* d_in, const int* in_sizes, int n_in,
                              void* d_out, int out_size, void* d_ws, size_t ws_size,
                              hipStream_t stream) {
  const float* z = (const float*)d_in[0];   // (16,256,32,32) fp32
  const float* cb = (const float*)d_in[1];  // (8192,256) fp32
  float* out = (float*)d_out;               // fp32: [z_q_st | loss | idx | perp]

  float* wsf = (float*)d_ws;
  int* hist = (int*)d_ws;                          // 8192 ints
  float* loss = wsf + 8192;                        // 1 (+pad)
  float* Bk = wsf + 8448;                          // 8192
  float* Arow = wsf + 16640;                       // 16384
  u64* rowBest = (u64*)(wsf + 33024);              // 16384 u64 (128 KB)
  ushort* cbB = (ushort*)(wsf + 65792);            // 2.10M ushorts (4.2 MB)
  float* cbT = wsf + 65792 + 1048576;              // 2M floats (8 MB)

  hipMemsetAsync(d_ws, 0, 8448 * sizeof(float), stream);
  hipMemsetAsync(rowBest, 0xFF, NROWS * sizeof(u64), stream);
  vq_prep<<<1632, 256, 0, stream>>>(z, cb, cbT, Bk, Arow, cbB);
  vq_fused<<<NROWS / MT, 256, 0, stream>>>(z, cbT, cb, cbB, Bk, Arow, out,
                                           hist, loss, rowBest);
  vq_final<<<1, 256, 0, stream>>>(hist, loss, out);
}